// Round 5
// baseline (92.331 us; speedup 1.0000x reference)
//
#include <hip/hip_runtime.h>
#include <math.h>

// Disable FP contraction file-wide so every rounding step is the one we wrote;
// fmas are explicit via fmaf() where we want to mimic the XLA/Eigen dot chain.
#pragma clang fp contract(off)

#define VOCAB 4096
#define NPTS  32768          // 4 * 8192
#define NELEM 98304          // NPTS * 3
#define BLOCK 256
#define NWAVE 4                      // waves per block
#define CPW   (VOCAB / NWAVE)        // 1024 codes scanned per wave
#define PTS_PER_BLOCK 64             // lane == point

// ---------------------------------------------------------------------------
// Kernel 0: pack the codebook as float4 (e0,e1,e2,||e||^2) into workspace.
// esq association matches the reference's sum(embed*embed, axis=1):
// (e0*e0 + e1*e1) + e2*e2, contract off.
// ---------------------------------------------------------------------------
__global__ __launch_bounds__(256) void vq_prep(
    const float* __restrict__ embed, float4* __restrict__ codes4)
{
  const int c = blockIdx.x * 256 + threadIdx.x;
  float e0 = embed[3 * c + 0];
  float e1 = embed[3 * c + 1];
  float e2 = embed[3 * c + 2];
  float esq = (e0 * e0 + e1 * e1) + e2 * e2;
  codes4[c] = make_float4(e0, e1, e2, esq);
}

// ---------------------------------------------------------------------------
// Kernel 1: nearest-code assignment + quant_st + idx + scatter (counts, sums)
// + SSE loss partial.
//
// Round-4 post-mortem: the 41.8 us was exactly the LDS port cost (8 waves/CU
// x 1024 ds_read_b128 x ~12 cyc = 41 us) -- LDS-issue bound, not VALU bound.
// This round the inner loop reads the packed codebook from GLOBAL memory at a
// wave-uniform address: wv is hoisted to an SGPR via readfirstlane and all
// pointers are __restrict__, so the compiler proves uniformity and emits
// s_load_dwordx4/x16 through the scalar cache. Zero LDS / vector-memory ops
// in the loop; code components enter the v_fma stream as SGPR operands
// (<=1 SGPR per VALU instruction, which is legal). ~9 VALU ops per eval is
// the whole loop: floor = 134M evals x 9 x 2cyc / 1024 SIMDs = 15.4 us.
//
// Each of the block's 64 lanes owns ONE point; the 4 waves split the
// codebook (wave w scans [1024w, 1024w+1024) ascending). Cross-wave combine
// via a tiny static LDS buffer; wave ranges ascending + lexicographic
// (d, idx) combine => exact argmin first-minimum semantics. Distance
// arithmetic is expression-for-expression identical to rounds 1-4 (absmax 0).
// ---------------------------------------------------------------------------
__global__ __launch_bounds__(BLOCK) void vq_assign(
    const float* __restrict__ feats, const float4* __restrict__ codes4,
    float* __restrict__ out_quant, float* __restrict__ out_idx,
    float* __restrict__ counts, float* __restrict__ sums,
    float* __restrict__ sse)
{
  __shared__ float dbuf[NWAVE][64];
  __shared__ int   ibuf[NWAVE][64];

  const int tid  = threadIdx.x;
  const int lane = tid & 63;
  const int wv   = __builtin_amdgcn_readfirstlane(tid >> 6);  // SGPR-uniform

  const int p = blockIdx.x * PTS_PER_BLOCK + lane;
  const float x0 = feats[3 * p + 0];
  const float x1 = feats[3 * p + 1];
  const float x2 = feats[3 * p + 2];
  const float xsq = (x0 * x0 + x1 * x1) + x2 * x2;

  float best = INFINITY;
  int   bidx = 0;
  const float4* wc = codes4 + wv * CPW;    // uniform base
  const int cbase = wv * CPW;

  #pragma unroll 16
  for (int k = 0; k < CPW; ++k) {
    float4 e = wc[k];                      // uniform addr -> s_load (SGPRs)
    // Eigen/XLA-style fma chain: ((x0*e0) fma x1*e1) fma x2*e2
    float dot = fmaf(x2, e.z, fmaf(x1, e.y, x0 * e.x));
    // (xsq - 2*dot) + esq -- exact association match with the reference
    float d = (xsq - 2.0f * dot) + e.w;
    if (d < best) { best = d; bidx = cbase + k; }  // strict <: first occurrence
  }

  dbuf[wv][lane] = best;
  ibuf[wv][lane] = bidx;
  __syncthreads();

  if (wv == 0) {
    #pragma unroll
    for (int w = 1; w < NWAVE; ++w) {
      float od = dbuf[w][lane];
      int   oi = ibuf[w][lane];
      // lexicographic (d, idx): wave ranges ascending => first-min semantics
      if (od < best || (od == best && oi < bidx)) { best = od; bidx = oi; }
    }

    // winning code values (bit-identical copies of embed rows)
    const float4 q = codes4[bidx];

    // quant_st = feats + (quant - feats), exactly as the reference evaluates
    out_quant[3 * p + 0] = x0 + (q.x - x0);
    out_quant[3 * p + 1] = x1 + (q.y - x1);
    out_quant[3 * p + 2] = x2 + (q.z - x2);
    out_idx[p] = (float)bidx;

    atomicAdd(&counts[bidx], 1.0f);
    atomicAdd(&sums[3 * bidx + 0], x0);
    atomicAdd(&sums[3 * bidx + 1], x1);
    atomicAdd(&sums[3 * bidx + 2], x2);

    float d0 = q.x - x0, d1 = q.y - x1, d2 = q.z - x2;
    float l = (d0 * d0 + d1 * d1) + d2 * d2;
    #pragma unroll
    for (int m = 1; m <= 32; m <<= 1) l += __shfl_xor(l, m, 64);
    if (lane == 0) atomicAdd(sse, l);
  }
}

// ---------------------------------------------------------------------------
// Kernel 2: EMA update, global n-reduction, normalized embed, loss finalize.
// Single 1024-thread block; shuffle-based n reduction (1 barrier).
// ---------------------------------------------------------------------------
__global__ __launch_bounds__(1024) void vq_ema(
    const float* __restrict__ counts, const float* __restrict__ sums,
    const float* __restrict__ sse,
    const float* __restrict__ ema_cs, const float* __restrict__ ema_w,
    float* __restrict__ out_loss, float* __restrict__ out_ncs,
    float* __restrict__ out_nw, float* __restrict__ out_nemb)
{
  __shared__ float part[16];
  const int tid = threadIdx.x;
  const float DEC = 0.99f;
  const float OMD = (float)(1.0 - 0.99);
  const float EPS = 1e-5f;

  float ncs[4];
  float nw[12];
  float nsum = 0.0f;

  #pragma unroll
  for (int k = 0; k < 4; ++k) {
    int v = k * 1024 + tid;
    float t = DEC * ema_cs[v] + OMD * counts[v];
    ncs[k] = t;
    out_ncs[v] = t;
    nsum += t;
    #pragma unroll
    for (int d = 0; d < 3; ++d) {
      float w = DEC * ema_w[3 * v + d] + OMD * sums[3 * v + d];
      nw[3 * k + d] = w;
      out_nw[3 * v + d] = w;
    }
  }

  #pragma unroll
  for (int m = 1; m <= 32; m <<= 1) nsum += __shfl_xor(nsum, m, 64);
  if ((tid & 63) == 0) part[tid >> 6] = nsum;
  __syncthreads();

  float n = 0.0f;
  #pragma unroll
  for (int i = 0; i < 16; ++i) n += part[i];
  const float denom = n + (float)VOCAB * EPS;

  #pragma unroll
  for (int k = 0; k < 4; ++k) {
    int v = k * 1024 + tid;
    float cs = (ncs[k] + EPS) / denom * n;
    #pragma unroll
    for (int d = 0; d < 3; ++d)
      out_nemb[3 * v + d] = nw[3 * k + d] / cs;
  }

  if (tid == 0) {
    float m = sse[0] / (float)NELEM;
    out_loss[0] = m + 0.25f * m;   // mean((q-f)^2) + 0.25*mean((f-q)^2)
  }
}

// ---------------------------------------------------------------------------
extern "C" void kernel_launch(void* const* d_in, const int* in_sizes, int n_in,
                              void* d_out, int out_size, void* d_ws, size_t ws_size,
                              hipStream_t stream) {
  const float* feats  = (const float*)d_in[0];   // (4,8192,3)
  const float* embed  = (const float*)d_in[1];   // (4096,3)
  const float* ema_cs = (const float*)d_in[2];   // (4096,)
  const float* ema_w  = (const float*)d_in[3];   // (4096,3)

  float* out      = (float*)d_out;
  float* o_quant  = out;                       // 98304
  float* o_idx    = out + 98304;               // 32768
  float* o_loss   = out + 131072;              // 1
  float* o_ncs    = out + 131073;              // 4096
  float* o_nw     = out + 135169;              // 12288
  float* o_nemb   = out + 147457;              // 12288

  float* ws_counts = (float*)d_ws;             // 4096
  float* ws_sums   = ws_counts + VOCAB;        // 12288
  float* ws_sse    = ws_sums + 3 * VOCAB;      // 1
  // 16400 floats = 65600 B so far; 65600 % 16 == 0 -> codes4 is 16B-aligned
  float4* ws_codes4 = (float4*)((float*)d_ws + 16400);   // 4096 float4 = 64 KiB

  hipMemsetAsync(d_ws, 0, (size_t)(VOCAB * 4 + 1) * sizeof(float), stream);

  vq_prep<<<VOCAB / 256, 256, 0, stream>>>(embed, ws_codes4);

  vq_assign<<<NPTS / PTS_PER_BLOCK, BLOCK, 0, stream>>>(
      feats, ws_codes4, o_quant, o_idx, ws_counts, ws_sums, ws_sse);

  vq_ema<<<1, 1024, 0, stream>>>(
      ws_counts, ws_sums, ws_sse, ema_cs, ema_w,
      o_loss, o_ncs, o_nw, o_nemb);
}

// Round 6
// 51.682 us; speedup vs baseline: 1.7865x; 1.7865x over previous
//
#include <hip/hip_runtime.h>
#include <math.h>

// Disable FP contraction file-wide so every rounding step is the one we wrote;
// fmas are explicit via fmaf() where we want to mimic the XLA/Eigen dot chain.
#pragma clang fp contract(off)

#define VOCAB 4096
#define NPTS  32768          // 4 * 8192
#define NELEM 98304          // NPTS * 3
#define BLOCK 512
#define NWAVE 8                      // waves per block
#define CPW   (VOCAB / NWAVE)        // 512 codes scanned per wave
#define PPL   2                      // points per lane
#define PTS_PER_BLOCK (64 * PPL)     // 128 points per block -> 256 blocks

// ---------------------------------------------------------------------------
// Kernel 1: nearest-code assignment + quant_st + idx + scatter (counts, sums)
// + SSE loss partial.
//
// Model (validated round 4): with the codebook in LDS the kernel is LDS-port
// bound -- each broadcast ds_read_b128 costs ~12 cyc of the per-CU LDS port.
// Round 4: 8 waves/CU x 1024 reads x 12 = 98k cyc = 41 us (measured 41.8).
// Round 5's scalar-cache path thrashed K$ (16KB vs 64KB working set): revert.
//
// This round: each lane owns TWO points, so each code read is amortized over
// 2 distance evals -> per-CU LDS cost halves to 8 x 512 x 12 = 49k cyc
// (~20.5 us), VALU (36.9k cyc, 15.4 us) hides underneath. 512-thread blocks,
// 8 waves split the codebook (wave w scans [512w, 512w+512) ascending);
// 256 blocks = 1/CU. Cross-wave combine via static LDS; wave ranges
// ascending + lexicographic (d, idx) combine => exact argmin first-min
// semantics. Distance arithmetic is expression-for-expression identical to
// the verified rounds 1-4 (absmax 0 in round 4).
// ---------------------------------------------------------------------------
__global__ __launch_bounds__(BLOCK) void vq_assign(
    const float* __restrict__ feats, const float* __restrict__ embed,
    float* __restrict__ out_quant, float* __restrict__ out_idx,
    float* __restrict__ counts, float* __restrict__ sums,
    float* __restrict__ sse)
{
  extern __shared__ float4 codes[];        // [VOCAB] = 64 KiB dynamic
  __shared__ float dbuf[NWAVE][PPL][64];   // 4 KiB
  __shared__ int   ibuf[NWAVE][PPL][64];   // 4 KiB

  const int tid  = threadIdx.x;
  const int lane = tid & 63;
  const int wv   = tid >> 6;

  // Stage codebook (e0,e1,e2,||e||^2) into LDS; esq association matches
  // the reference's sum(embed*embed, axis=1): (e0*e0 + e1*e1) + e2*e2.
  for (int c = tid; c < VOCAB; c += BLOCK) {
    float e0 = embed[3 * c + 0];
    float e1 = embed[3 * c + 1];
    float e2 = embed[3 * c + 2];
    float esq = (e0 * e0 + e1 * e1) + e2 * e2;
    codes[c] = make_float4(e0, e1, e2, esq);
  }
  __syncthreads();

  // Lane owns points pbase+lane (slot 0) and pbase+64+lane (slot 1).
  const int pbase = blockIdx.x * PTS_PER_BLOCK;
  float px[PPL][3], xsq[PPL];
  #pragma unroll
  for (int s = 0; s < PPL; ++s) {
    const int p = pbase + s * 64 + lane;
    px[s][0] = feats[3 * p + 0];
    px[s][1] = feats[3 * p + 1];
    px[s][2] = feats[3 * p + 2];
    xsq[s] = (px[s][0] * px[s][0] + px[s][1] * px[s][1]) + px[s][2] * px[s][2];
  }

  float best[PPL] = {INFINITY, INFINITY};
  int   bidx[PPL] = {0, 0};
  const float4* wc = codes + wv * CPW;
  const int cbase = wv * CPW;

  #pragma unroll 16
  for (int k = 0; k < CPW; ++k) {
    float4 e = wc[k];                      // wave-uniform addr -> broadcast
    #pragma unroll
    for (int s = 0; s < PPL; ++s) {
      // Eigen/XLA-style fma chain: ((x0*e0) fma x1*e1) fma x2*e2
      float dot = fmaf(px[s][2], e.z, fmaf(px[s][1], e.y, px[s][0] * e.x));
      // (xsq - 2*dot) + esq -- exact association match with the reference
      float d = (xsq[s] - 2.0f * dot) + e.w;
      if (d < best[s]) { best[s] = d; bidx[s] = cbase + k; }  // strict <
    }
  }

  #pragma unroll
  for (int s = 0; s < PPL; ++s) {
    dbuf[wv][s][lane] = best[s];
    ibuf[wv][s][lane] = bidx[s];
  }
  __syncthreads();

  if (wv == 0) {
    #pragma unroll
    for (int s = 0; s < PPL; ++s) {
      float b = best[s];
      int   bi = bidx[s];
      #pragma unroll
      for (int w = 1; w < NWAVE; ++w) {
        float od = dbuf[w][s][lane];
        int   oi = ibuf[w][s][lane];
        // lexicographic (d, idx): wave ranges ascending => first-min
        if (od < b || (od == b && oi < bi)) { b = od; bi = oi; }
      }

      const int p = pbase + s * 64 + lane;
      const float4 q = codes[bi];          // codebook still live in LDS
      const float x0 = px[s][0], x1 = px[s][1], x2 = px[s][2];

      // quant_st = feats + (quant - feats), exactly as the reference does
      out_quant[3 * p + 0] = x0 + (q.x - x0);
      out_quant[3 * p + 1] = x1 + (q.y - x1);
      out_quant[3 * p + 2] = x2 + (q.z - x2);
      out_idx[p] = (float)bi;

      atomicAdd(&counts[bi], 1.0f);
      atomicAdd(&sums[3 * bi + 0], x0);
      atomicAdd(&sums[3 * bi + 1], x1);
      atomicAdd(&sums[3 * bi + 2], x2);

      float d0 = q.x - x0, d1 = q.y - x1, d2 = q.z - x2;
      float l = (d0 * d0 + d1 * d1) + d2 * d2;
      #pragma unroll
      for (int m = 1; m <= 32; m <<= 1) l += __shfl_xor(l, m, 64);
      if (lane == 0) atomicAdd(sse, l);
    }
  }
}

// ---------------------------------------------------------------------------
// Kernel 2: EMA update, global n-reduction, normalized embed, loss finalize.
// Single 1024-thread block; shuffle-based n reduction (1 barrier).
// ---------------------------------------------------------------------------
__global__ __launch_bounds__(1024) void vq_ema(
    const float* __restrict__ counts, const float* __restrict__ sums,
    const float* __restrict__ sse,
    const float* __restrict__ ema_cs, const float* __restrict__ ema_w,
    float* __restrict__ out_loss, float* __restrict__ out_ncs,
    float* __restrict__ out_nw, float* __restrict__ out_nemb)
{
  __shared__ float part[16];
  const int tid = threadIdx.x;
  const float DEC = 0.99f;
  const float OMD = (float)(1.0 - 0.99);
  const float EPS = 1e-5f;

  float ncs[4];
  float nw[12];
  float nsum = 0.0f;

  #pragma unroll
  for (int k = 0; k < 4; ++k) {
    int v = k * 1024 + tid;
    float t = DEC * ema_cs[v] + OMD * counts[v];
    ncs[k] = t;
    out_ncs[v] = t;
    nsum += t;
    #pragma unroll
    for (int d = 0; d < 3; ++d) {
      float w = DEC * ema_w[3 * v + d] + OMD * sums[3 * v + d];
      nw[3 * k + d] = w;
      out_nw[3 * v + d] = w;
    }
  }

  #pragma unroll
  for (int m = 1; m <= 32; m <<= 1) nsum += __shfl_xor(nsum, m, 64);
  if ((tid & 63) == 0) part[tid >> 6] = nsum;
  __syncthreads();

  float n = 0.0f;
  #pragma unroll
  for (int i = 0; i < 16; ++i) n += part[i];
  const float denom = n + (float)VOCAB * EPS;

  #pragma unroll
  for (int k = 0; k < 4; ++k) {
    int v = k * 1024 + tid;
    float cs = (ncs[k] + EPS) / denom * n;
    #pragma unroll
    for (int d = 0; d < 3; ++d)
      out_nemb[3 * v + d] = nw[3 * k + d] / cs;
  }

  if (tid == 0) {
    float m = sse[0] / (float)NELEM;
    out_loss[0] = m + 0.25f * m;   // mean((q-f)^2) + 0.25*mean((f-q)^2)
  }
}

// ---------------------------------------------------------------------------
extern "C" void kernel_launch(void* const* d_in, const int* in_sizes, int n_in,
                              void* d_out, int out_size, void* d_ws, size_t ws_size,
                              hipStream_t stream) {
  const float* feats  = (const float*)d_in[0];   // (4,8192,3)
  const float* embed  = (const float*)d_in[1];   // (4096,3)
  const float* ema_cs = (const float*)d_in[2];   // (4096,)
  const float* ema_w  = (const float*)d_in[3];   // (4096,3)

  float* out      = (float*)d_out;
  float* o_quant  = out;                       // 98304
  float* o_idx    = out + 98304;               // 32768
  float* o_loss   = out + 131072;              // 1
  float* o_ncs    = out + 131073;              // 4096
  float* o_nw     = out + 135169;              // 12288
  float* o_nemb   = out + 147457;              // 12288

  float* ws_counts = (float*)d_ws;             // 4096
  float* ws_sums   = ws_counts + VOCAB;        // 12288
  float* ws_sse    = ws_sums + 3 * VOCAB;      // 1

  hipMemsetAsync(d_ws, 0, (size_t)(VOCAB * 4 + 1) * sizeof(float), stream);

  vq_assign<<<NPTS / PTS_PER_BLOCK, BLOCK, VOCAB * sizeof(float4), stream>>>(
      feats, embed, o_quant, o_idx, ws_counts, ws_sums, ws_sse);

  vq_ema<<<1, 1024, 0, stream>>>(
      ws_counts, ws_sums, ws_sse, ema_cs, ema_w,
      o_loss, o_ncs, o_nw, o_nemb);
}

// Round 7
// 50.334 us; speedup vs baseline: 1.8344x; 1.0268x over previous
//
#include <hip/hip_runtime.h>
#include <math.h>

// Disable FP contraction file-wide so every rounding step is the one we wrote;
// fmas are explicit via fmaf() where we want to mimic the XLA/Eigen dot chain.
#pragma clang fp contract(off)

#define VOCAB 4096
#define NPTS  32768          // 4 * 8192
#define NELEM 98304          // NPTS * 3
#define BLOCK 1024
#define NWAVE 16                     // waves per block
#define CPW   (VOCAB / NWAVE)        // 256 codes scanned per wave
#define PPL   2                      // points per lane
#define PTS_PER_BLOCK (64 * PPL)     // 128 points per block -> 256 blocks

// ---------------------------------------------------------------------------
// Kernel 1: nearest-code assignment + quant_st + idx + scatter (counts, sums)
// + SSE loss partial.
//
// Model history:
//  - r4 (PPL=1, 8 waves/CU): LDS-port bound, 8192 reads/CU x 12cyc = 41 us ==
//    measured 41.8. Port model validated.
//  - r5 (scalar K$ path): thrashed the 16KB constant cache, 80 us. Reverted.
//  - r6 (PPL=2, 8 waves/CU): port floor 20.5 us but measured 41 us at
//    VALUBusy 72% -- latency/issue bound: only 2 waves/SIMD and 36 VGPRs of
//    load buffering can't hide the ds_read->18-VALU dependent chain.
//
// This round: same PPL=2 port pressure (4096 reads/CU, 20.5 us floor) but
// 1024-thread blocks = 16 waves = 4 waves/SIMD for 2x latency hiding.
// Wave w scans codes [256w, 256w+256) ascending; each lane owns 2 points.
// Cross-wave combine via static LDS; wave ranges ascending + lexicographic
// (d, idx) combine => exact argmin first-min semantics. Distance arithmetic
// is expression-for-expression identical to the verified rounds (absmax 0).
// ---------------------------------------------------------------------------
__global__ __launch_bounds__(BLOCK) void vq_assign(
    const float* __restrict__ feats, const float* __restrict__ embed,
    float* __restrict__ out_quant, float* __restrict__ out_idx,
    float* __restrict__ counts, float* __restrict__ sums,
    float* __restrict__ sse)
{
  extern __shared__ float4 codes[];        // [VOCAB] = 64 KiB dynamic
  __shared__ float dbuf[NWAVE][PPL][64];   // 8 KiB
  __shared__ int   ibuf[NWAVE][PPL][64];   // 8 KiB

  const int tid  = threadIdx.x;
  const int lane = tid & 63;
  const int wv   = tid >> 6;

  // Stage codebook (e0,e1,e2,||e||^2) into LDS; esq association matches
  // the reference's sum(embed*embed, axis=1): (e0*e0 + e1*e1) + e2*e2.
  for (int c = tid; c < VOCAB; c += BLOCK) {
    float e0 = embed[3 * c + 0];
    float e1 = embed[3 * c + 1];
    float e2 = embed[3 * c + 2];
    float esq = (e0 * e0 + e1 * e1) + e2 * e2;
    codes[c] = make_float4(e0, e1, e2, esq);
  }
  __syncthreads();

  // Lane owns points pbase+lane (slot 0) and pbase+64+lane (slot 1).
  const int pbase = blockIdx.x * PTS_PER_BLOCK;
  float px[PPL][3], xsq[PPL];
  #pragma unroll
  for (int s = 0; s < PPL; ++s) {
    const int p = pbase + s * 64 + lane;
    px[s][0] = feats[3 * p + 0];
    px[s][1] = feats[3 * p + 1];
    px[s][2] = feats[3 * p + 2];
    xsq[s] = (px[s][0] * px[s][0] + px[s][1] * px[s][1]) + px[s][2] * px[s][2];
  }

  float best[PPL] = {INFINITY, INFINITY};
  int   bidx[PPL] = {0, 0};
  const float4* wc = codes + wv * CPW;
  const int cbase = wv * CPW;

  #pragma unroll 16
  for (int k = 0; k < CPW; ++k) {
    float4 e = wc[k];                      // wave-uniform addr -> broadcast
    #pragma unroll
    for (int s = 0; s < PPL; ++s) {
      // Eigen/XLA-style fma chain: ((x0*e0) fma x1*e1) fma x2*e2
      float dot = fmaf(px[s][2], e.z, fmaf(px[s][1], e.y, px[s][0] * e.x));
      // (xsq - 2*dot) + esq -- exact association match with the reference
      float d = (xsq[s] - 2.0f * dot) + e.w;
      if (d < best[s]) { best[s] = d; bidx[s] = cbase + k; }  // strict <
    }
  }

  #pragma unroll
  for (int s = 0; s < PPL; ++s) {
    dbuf[wv][s][lane] = best[s];
    ibuf[wv][s][lane] = bidx[s];
  }
  __syncthreads();

  if (wv == 0) {
    #pragma unroll
    for (int s = 0; s < PPL; ++s) {
      float b = best[s];
      int   bi = bidx[s];
      #pragma unroll
      for (int w = 1; w < NWAVE; ++w) {
        float od = dbuf[w][s][lane];
        int   oi = ibuf[w][s][lane];
        // lexicographic (d, idx): wave ranges ascending => first-min
        if (od < b || (od == b && oi < bi)) { b = od; bi = oi; }
      }

      const int p = pbase + s * 64 + lane;
      const float4 q = codes[bi];          // codebook still live in LDS
      const float x0 = px[s][0], x1 = px[s][1], x2 = px[s][2];

      // quant_st = feats + (quant - feats), exactly as the reference does
      out_quant[3 * p + 0] = x0 + (q.x - x0);
      out_quant[3 * p + 1] = x1 + (q.y - x1);
      out_quant[3 * p + 2] = x2 + (q.z - x2);
      out_idx[p] = (float)bi;

      atomicAdd(&counts[bi], 1.0f);
      atomicAdd(&sums[3 * bi + 0], x0);
      atomicAdd(&sums[3 * bi + 1], x1);
      atomicAdd(&sums[3 * bi + 2], x2);

      float d0 = q.x - x0, d1 = q.y - x1, d2 = q.z - x2;
      float l = (d0 * d0 + d1 * d1) + d2 * d2;
      #pragma unroll
      for (int m = 1; m <= 32; m <<= 1) l += __shfl_xor(l, m, 64);
      if (lane == 0) atomicAdd(sse, l);
    }
  }
}

// ---------------------------------------------------------------------------
// Kernel 2: EMA update, global n-reduction, normalized embed, loss finalize.
// Single 1024-thread block; shuffle-based n reduction (1 barrier).
// ---------------------------------------------------------------------------
__global__ __launch_bounds__(1024) void vq_ema(
    const float* __restrict__ counts, const float* __restrict__ sums,
    const float* __restrict__ sse,
    const float* __restrict__ ema_cs, const float* __restrict__ ema_w,
    float* __restrict__ out_loss, float* __restrict__ out_ncs,
    float* __restrict__ out_nw, float* __restrict__ out_nemb)
{
  __shared__ float part[16];
  const int tid = threadIdx.x;
  const float DEC = 0.99f;
  const float OMD = (float)(1.0 - 0.99);
  const float EPS = 1e-5f;

  float ncs[4];
  float nw[12];
  float nsum = 0.0f;

  #pragma unroll
  for (int k = 0; k < 4; ++k) {
    int v = k * 1024 + tid;
    float t = DEC * ema_cs[v] + OMD * counts[v];
    ncs[k] = t;
    out_ncs[v] = t;
    nsum += t;
    #pragma unroll
    for (int d = 0; d < 3; ++d) {
      float w = DEC * ema_w[3 * v + d] + OMD * sums[3 * v + d];
      nw[3 * k + d] = w;
      out_nw[3 * v + d] = w;
    }
  }

  #pragma unroll
  for (int m = 1; m <= 32; m <<= 1) nsum += __shfl_xor(nsum, m, 64);
  if ((tid & 63) == 0) part[tid >> 6] = nsum;
  __syncthreads();

  float n = 0.0f;
  #pragma unroll
  for (int i = 0; i < 16; ++i) n += part[i];
  const float denom = n + (float)VOCAB * EPS;

  #pragma unroll
  for (int k = 0; k < 4; ++k) {
    int v = k * 1024 + tid;
    float cs = (ncs[k] + EPS) / denom * n;
    #pragma unroll
    for (int d = 0; d < 3; ++d)
      out_nemb[3 * v + d] = nw[3 * k + d] / cs;
  }

  if (tid == 0) {
    float m = sse[0] / (float)NELEM;
    out_loss[0] = m + 0.25f * m;   // mean((q-f)^2) + 0.25*mean((f-q)^2)
  }
}

// ---------------------------------------------------------------------------
extern "C" void kernel_launch(void* const* d_in, const int* in_sizes, int n_in,
                              void* d_out, int out_size, void* d_ws, size_t ws_size,
                              hipStream_t stream) {
  const float* feats  = (const float*)d_in[0];   // (4,8192,3)
  const float* embed  = (const float*)d_in[1];   // (4096,3)
  const float* ema_cs = (const float*)d_in[2];   // (4096,)
  const float* ema_w  = (const float*)d_in[3];   // (4096,3)

  float* out      = (float*)d_out;
  float* o_quant  = out;                       // 98304
  float* o_idx    = out + 98304;               // 32768
  float* o_loss   = out + 131072;              // 1
  float* o_ncs    = out + 131073;              // 4096
  float* o_nw     = out + 135169;              // 12288
  float* o_nemb   = out + 147457;              // 12288

  float* ws_counts = (float*)d_ws;             // 4096
  float* ws_sums   = ws_counts + VOCAB;        // 12288
  float* ws_sse    = ws_sums + 3 * VOCAB;      // 1

  hipMemsetAsync(d_ws, 0, (size_t)(VOCAB * 4 + 1) * sizeof(float), stream);

  vq_assign<<<NPTS / PTS_PER_BLOCK, BLOCK, VOCAB * sizeof(float4), stream>>>(
      feats, embed, o_quant, o_idx, ws_counts, ws_sums, ws_sse);

  vq_ema<<<1, 1024, 0, stream>>>(
      ws_counts, ws_sums, ws_sse, ema_cs, ema_w,
      o_loss, o_ncs, o_nw, o_nemb);
}